// Round 3
// baseline (423.454 us; speedup 1.0000x reference)
//
#include <hip/hip_runtime.h>
#include <hip/hip_bf16.h>
#include <stdint.h>

#define NT 16320      // 64 * 255
#define NTPAD 16384
#define KDIM 128      // padded from 100
#define NCOLS 4096    // K*K
#define NSEQ 64
#define TSTEPS 255
#define VOCAB 32000
#define EDIM 100
#define KST 64        // number of HMM states
#define CHUNKS 17
#define CLEN 15       // 17*15 = 255

typedef __attribute__((ext_vector_type(8))) short s8v;
typedef __attribute__((ext_vector_type(4))) float f4v;

__device__ __forceinline__ float bfhi(uint32_t u) { return __uint_as_float(u & 0xffff0000u); }
__device__ __forceinline__ float bflo(uint32_t u) { return __uint_as_float(u << 16); }

// ---------------- prep A: gather embeddings -> bf16, K-pad to 128 -------------
__global__ void prep_a(const int* __restrict__ x, const float* __restrict__ emb,
                       __hip_bfloat16* __restrict__ A) {
    int m = blockIdx.x;          // 0..16383
    int e = threadIdx.x;         // 0..127
    float val = 0.f;
    if (m < NT) {
        int n = m / TSTEPS;
        int t = m - n * TSTEPS;
        int tok = x[n * 256 + t];
        if (e < EDIM) val = emb[(size_t)tok * EDIM + e];
    }
    A[(size_t)m * KDIM + e] = __float2bfloat16(val);
}

// ---------------- prep B: W_trans -> bf16, K-pad ------------------------------
__global__ void prep_b(const float* __restrict__ Wt, __hip_bfloat16* __restrict__ B) {
    int c = blockIdx.x;          // 0..4095
    int e = threadIdx.x;         // 0..127
    float val = (e < EDIM) ? Wt[(size_t)c * EDIM + e] : 0.f;
    B[(size_t)c * KDIM + e] = __float2bfloat16(val);
}

// ---------------- GEMM: S[m][c] = sum_k A[m][k]*B[c][k], bf16 MFMA ------------
// Epilogue: acc -> LDS (scattered 2B, <=2-way bank alias = free) -> coalesced
// row-major dwordx4 stores (64B-aligned full segments).
__global__ __launch_bounds__(256) void gemm_kern(const short* __restrict__ A,
                                                 const short* __restrict__ B,
                                                 __hip_bfloat16* __restrict__ S) {
    int mblk = blockIdx.x;   // 0..255
    int nblk = blockIdx.y;   // 0..63
    int wave = threadIdx.x >> 6;
    int lane = threadIdx.x & 63;
    int m_base = mblk * 64 + wave * 16;
    int c_base0 = nblk * 64;
    int row_a = m_base + (lane & 15);
    int k0 = (lane >> 4) * 8;

    __shared__ __hip_bfloat16 sT[64 * 72];

    f4v acc[4] = {};
    for (int kk = 0; kk < 4; ++kk) {
        int k = kk * 32 + k0;
        s8v a = *(const s8v*)(A + (size_t)row_a * KDIM + k);
#pragma unroll
        for (int sub = 0; sub < 4; ++sub) {
            int c = c_base0 + sub * 16 + (lane & 15);
            s8v b = *(const s8v*)(B + (size_t)c * KDIM + k);
            acc[sub] = __builtin_amdgcn_mfma_f32_16x16x32_bf16(a, b, acc[sub], 0, 0, 0);
        }
    }
    // acc layout: tile-col = sub*16 + (lane&15), tile-row = wave*16 + (lane>>4)*4 + r
    int trow0 = wave * 16 + (lane >> 4) * 4;
    int c15 = lane & 15;
#pragma unroll
    for (int sub = 0; sub < 4; ++sub) {
#pragma unroll
        for (int r = 0; r < 4; ++r) {
            sT[(trow0 + r) * 72 + sub * 16 + c15] = __float2bfloat16(acc[sub][r]);
        }
    }
    __syncthreads();

    // coalesced store: thread T -> tile row T>>2, col strip (T&3)*16
    int row = threadIdx.x >> 2;
    int q = threadIdx.x & 3;
    int m = mblk * 64 + row;
    if (m < NT) {
        const uint4* src = (const uint4*)&sT[row * 72 + q * 16];
        uint4* dst = (uint4*)(S + (size_t)m * NCOLS + c_base0 + q * 16);
        dst[0] = src[0];
        dst[1] = src[1];
    }
}

// ---------------- emission denominators: partial online-lse over vocab --------
__global__ __launch_bounds__(256) void dkern(const float* __restrict__ ec,
                                             const float* __restrict__ vw,
                                             float* __restrict__ partials) {
    __shared__ float ecT[64 * 64];
    int tid = threadIdx.x;
    for (int idx = tid; idx < 4096; idx += 256) {
        int k = idx >> 6, e = idx & 63;
        ecT[e * 64 + k] = ec[idx];
    }
    __syncthreads();
    int wave = tid >> 6, lane = tid & 63;
    int v0 = blockIdx.x * 125;
    float m = -1e30f, s = 0.f;
    for (int v = v0 + wave; v < v0 + 125; v += 4) {
        const float* row = vw + (size_t)v * 64;
        float acc = 0.f;
#pragma unroll
        for (int e = 0; e < 64; ++e) acc += ecT[e * 64 + lane] * row[e];
        float nm = fmaxf(m, acc);
        s = s * __expf(m - nm) + __expf(acc - nm);
        m = nm;
    }
    __shared__ float pm[4][64], ps[4][64];
    pm[wave][lane] = m; ps[wave][lane] = s;
    __syncthreads();
    if (tid < 64) {
        float M = pm[0][tid], Ssum = ps[0][tid];
#pragma unroll
        for (int w = 1; w < 4; ++w) {
            float m2 = pm[w][tid], s2 = ps[w][tid];
            float nm = fmaxf(M, m2);
            Ssum = Ssum * __expf(M - nm) + s2 * __expf(m2 - nm);
            M = nm;
        }
        partials[(blockIdx.x * 64 + tid) * 2]     = M;
        partials[(blockIdx.x * 64 + tid) * 2 + 1] = Ssum;
    }
}

__global__ void dreduce(const float* __restrict__ partials, float* __restrict__ d) {
    int k = threadIdx.x;   // 64 threads
    float M = -1e30f, S = 0.f;
    for (int b = 0; b < 256; ++b) {
        float m2 = partials[(b * 64 + k) * 2];
        float s2 = partials[(b * 64 + k) * 2 + 1];
        float nm = fmaxf(M, m2);
        S = S * __expf(M - nm) + s2 * __expf(m2 - nm);
        M = nm;
    }
    d[k] = M + __logf(S);
}

// ---------------- emissions for observed tokens -------------------------------
__global__ __launch_bounds__(256) void emit_kern(const int* __restrict__ x,
                                                 const float* __restrict__ ec,
                                                 const float* __restrict__ vw,
                                                 const float* __restrict__ d,
                                                 float* __restrict__ emit) {
    __shared__ float ecT[64 * 64];
    int tid = threadIdx.x;
    for (int idx = tid; idx < 4096; idx += 256) {
        int k = idx >> 6, e = idx & 63;
        ecT[e * 64 + k] = ec[idx];
    }
    __syncthreads();
    int wave = tid >> 6, lane = tid & 63;
    int nt = blockIdx.x * 4 + wave;      // grid = 4080 -> exactly 16320
    int n = nt / TSTEPS;
    int t = nt - n * TSTEPS;
    int tok = x[n * 256 + t + 1];
    const float* row = vw + (size_t)tok * 64;
    float acc = 0.f;
#pragma unroll
    for (int e = 0; e < 64; ++e) acc += ecT[e * 64 + lane] * row[e];
    emit[(size_t)nt * 64 + lane] = acc - d[lane];
}

// ---------------- chunk kernel: log-semiring product of 15 step-matrices ------
__global__ __launch_bounds__(256) void chunk_kern(const __hip_bfloat16* __restrict__ S,
                                                  const float* __restrict__ emitw,
                                                  __hip_bfloat16* __restrict__ Gout,
                                                  float* __restrict__ Rout) {
    int n = blockIdx.x, c = blockIdx.y;
    int tid = threadIdx.x, wave = tid >> 6, lane = tid & 63;

    __shared__ __align__(16) float sX[64 * 65];            // exp(S - rowmax), fp32
    __shared__ __align__(16) __hip_bfloat16 sE[64 * 72];   // E^T: sE[j*72+i] = E[i][j]
    __shared__ __align__(16) __hip_bfloat16 sG[64 * 72];   // Gexp: sG[a*72+i]
    __shared__ float sR[64];
    __shared__ float sRowInv[64];
    __shared__ float sEm[64];

    // init G = identity (exp-domain), r = 0
    for (int idx = tid; idx < 4096; idx += 256) {
        int a = idx >> 6, i = idx & 63;
        sG[a * 72 + i] = __float2bfloat16(a == i ? 1.f : 0.f);
    }
    if (tid < 64) sR[tid] = 0.f;
    __syncthreads();

    const __hip_bfloat16* Sn = S + ((size_t)(n * TSTEPS + c * CLEN)) * NCOLS;
    const float* em_n = emitw + (size_t)n * TSTEPS * 64 + (size_t)c * CLEN * 64;

    int i_a = tid >> 2, q = tid & 3;   // pass (a): row i_a, col strip q*16

    for (int tl = 0; tl < CLEN; ++tl) {
        // ---- (a) load S tile strip, rowmax/rowsum, write X = exp(S - rm) ----
        const uint4* sp = (const uint4*)(Sn + (size_t)tl * NCOLS + i_a * 64 + q * 16);
        uint4 r0 = sp[0], r1 = sp[1];
        float f[16];
        {
            const uint32_t* u = (const uint32_t*)&r0;
#pragma unroll
            for (int i = 0; i < 4; ++i) { f[2*i] = bflo(u[i]); f[2*i+1] = bfhi(u[i]); }
            const uint32_t* u2 = (const uint32_t*)&r1;
#pragma unroll
            for (int i = 0; i < 4; ++i) { f[8+2*i] = bflo(u2[i]); f[8+2*i+1] = bfhi(u2[i]); }
        }
        float m = f[0];
#pragma unroll
        for (int k = 1; k < 16; ++k) m = fmaxf(m, f[k]);
        m = fmaxf(m, __shfl_xor(m, 1, 64));
        m = fmaxf(m, __shfl_xor(m, 2, 64));
        float sig = 0.f;
        float xv[16];
#pragma unroll
        for (int k = 0; k < 16; ++k) { xv[k] = __expf(f[k] - m); sig += xv[k]; }
        sig += __shfl_xor(sig, 1, 64);
        sig += __shfl_xor(sig, 2, 64);
        float* xd = sX + i_a * 65 + q * 16;
#pragma unroll
        for (int k = 0; k < 16; ++k) xd[k] = xv[k];
        if (q == 0) sRowInv[i_a] = 1.0f / sig;
        if (tid < 64) sEm[tid] = __expf(em_n[tl * 64 + tid]);
        __syncthreads();

        // ---- (b) E^T[j][i] = X[i][j] * e^{em_j} / sigma_i, bf16 -------------
        {
            float emj = sEm[lane];
#pragma unroll
            for (int r = 0; r < 16; r += 2) {
                int i = wave * 16 + r;
                float v0 = sX[i * 65 + lane] * emj * sRowInv[i];
                float v1 = sX[(i + 1) * 65 + lane] * emj * sRowInv[i + 1];
                union { __hip_bfloat16 h[2]; uint32_t u; } p;
                p.h[0] = __float2bfloat16(v0);
                p.h[1] = __float2bfloat16(v1);
                *(uint32_t*)&sE[lane * 72 + i] = p.u;
            }
        }
        __syncthreads();

        // ---- (c) P = Gexp . E via MFMA: wave handles rows [16w,16w+16) ------
        f4v acc[4] = {};
        int arow = wave * 16 + (lane & 15);
        int koff = (lane >> 4) * 8;
#pragma unroll
        for (int kk = 0; kk < 2; ++kk) {
            s8v a = *(const s8v*)(sG + arow * 72 + kk * 32 + koff);
#pragma unroll
            for (int jt = 0; jt < 4; ++jt) {
                s8v b = *(const s8v*)(sE + (jt * 16 + (lane & 15)) * 72 + kk * 32 + koff);
                acc[jt] = __builtin_amdgcn_mfma_f32_16x16x32_bf16(a, b, acc[jt], 0, 0, 0);
            }
        }

        // ---- (d) rowmax-normalize P -> Gexp, r += log(rowmax) ---------------
        float rmx[4];
#pragma unroll
        for (int rr = 0; rr < 4; ++rr) {
            float mm = acc[0][rr];
#pragma unroll
            for (int jt = 1; jt < 4; ++jt) mm = fmaxf(mm, acc[jt][rr]);
            mm = fmaxf(mm, __shfl_xor(mm, 1, 64));
            mm = fmaxf(mm, __shfl_xor(mm, 2, 64));
            mm = fmaxf(mm, __shfl_xor(mm, 4, 64));
            mm = fmaxf(mm, __shfl_xor(mm, 8, 64));
            rmx[rr] = fmaxf(mm, 1e-35f);
        }
#pragma unroll
        for (int rr = 0; rr < 4; ++rr) {
            int row = wave * 16 + (lane >> 4) * 4 + rr;
            float inv = 1.0f / rmx[rr];
#pragma unroll
            for (int jt = 0; jt < 4; ++jt)
                sG[row * 72 + jt * 16 + (lane & 15)] = __float2bfloat16(acc[jt][rr] * inv);
        }
        if ((lane & 15) == 0) {
#pragma unroll
            for (int rr = 0; rr < 4; ++rr) {
                int row = wave * 16 + (lane >> 4) * 4 + rr;
                sR[row] += __logf(rmx[rr]);
            }
        }
        __syncthreads();
    }

    // ---- output: compact Gexp + row scales ----
    __hip_bfloat16* go = Gout + ((size_t)(n * CHUNKS + c)) * 4096;
    for (int idx = tid; idx < 4096; idx += 256) {
        int a = idx >> 6, i = idx & 63;
        go[idx] = sG[a * 72 + i];
    }
    if (tid < 64) Rout[(size_t)(n * CHUNKS + c) * 64 + tid] = sR[tid];
}

// ---------------- combine: alpha0 through 17 chunk matrices -------------------
__global__ __launch_bounds__(256) void combine_kern(const __hip_bfloat16* __restrict__ G,
                                                    const float* __restrict__ R,
                                                    const float* __restrict__ sw,
                                                    const float* __restrict__ sb,
                                                    float* __restrict__ out) {
    int n = blockIdx.x;
    int tid = threadIdx.x, wave = tid >> 6, lane = tid & 63;
    __shared__ float sA[64], sV[64], pw[4][64];
    __shared__ float sMx;

    if (tid < 64) {
        float v = sw[tid] + sb[tid];
        float m = v;
        for (int off = 1; off < 64; off <<= 1) m = fmaxf(m, __shfl_xor(m, off, 64));
        float s = __expf(v - m);
        for (int off = 1; off < 64; off <<= 1) s += __shfl_xor(s, off, 64);
        sA[tid] = v - (m + __logf(s));
    }
    __syncthreads();

    for (int c = 0; c < CHUNKS; ++c) {
        const __hip_bfloat16* Gc = G + ((size_t)(n * CHUNKS + c)) * 4096;
        const float* Rc = R + (size_t)(n * CHUNKS + c) * 64;
        if (tid < 64) {
            float t = sA[tid] + Rc[tid];
            float m = t;
            for (int off = 1; off < 64; off <<= 1) m = fmaxf(m, __shfl_xor(m, off, 64));
            sV[tid] = __expf(t - m);
            if (tid == 0) sMx = m;
        }
        __syncthreads();
        float part = 0.f;
        int i0 = wave * 16;
#pragma unroll
        for (int r = 0; r < 16; ++r)
            part += sV[i0 + r] * __bfloat162float(Gc[(i0 + r) * 64 + lane]);
        pw[wave][lane] = part;
        __syncthreads();
        if (tid < 64) {
            float w = pw[0][tid] + pw[1][tid] + pw[2][tid] + pw[3][tid];
            sA[tid] = sMx + __logf(w);
        }
        __syncthreads();
    }

    if (tid < 64) {
        float v = sA[tid];
        float m = v;
        for (int off = 1; off < 64; off <<= 1) m = fmaxf(m, __shfl_xor(m, off, 64));
        float s = __expf(v - m);
        for (int off = 1; off < 64; off <<= 1) s += __shfl_xor(s, off, 64);
        if (tid == 0) atomicAdd(out, -(m + __logf(s)) * (1.0f / 64.0f));
    }
}

extern "C" void kernel_launch(void* const* d_in, const int* in_sizes, int n_in,
                              void* d_out, int out_size, void* d_ws, size_t ws_size,
                              hipStream_t stream) {
    const int*   x   = (const int*)d_in[0];
    const float* emb = (const float*)d_in[1];
    const float* Wt  = (const float*)d_in[2];
    const float* sw  = (const float*)d_in[3];
    const float* sb  = (const float*)d_in[4];
    const float* ec  = (const float*)d_in[5];
    const float* vw  = (const float*)d_in[6];
    float* out = (float*)d_out;
    char* ws = (char*)d_ws;

    __hip_bfloat16* S  = (__hip_bfloat16*)ws;                          // 133,693,440 B
    __hip_bfloat16* A  = (__hip_bfloat16*)(ws + 133693440ull);         //   4,194,304 B
    __hip_bfloat16* B  = (__hip_bfloat16*)(ws + 137887744ull);         //   1,048,576 B
    float* emitw       = (float*)(ws + 138936320ull);                  //   4,177,920 B
    float* dvec        = (float*)(ws + 143114240ull);                  //       1,024 B
    float* partials    = (float*)(ws + 143115264ull);                  //     131,072 B
    __hip_bfloat16* Gc = (__hip_bfloat16*)(ws + 143246336ull);         //   8,912,896 B
    float* Rc          = (float*)(ws + 152159232ull);                  //     278,528 B
                                                                       // end 152,437,760

    hipMemsetAsync(out, 0, sizeof(float), stream);

    prep_a<<<NTPAD, 128, 0, stream>>>(x, emb, A);
    prep_b<<<NCOLS, 128, 0, stream>>>(Wt, B);
    gemm_kern<<<dim3(NTPAD / 64, NCOLS / 64), 256, 0, stream>>>((const short*)A, (const short*)B, S);
    dkern<<<256, 256, 0, stream>>>(ec, vw, partials);
    dreduce<<<1, 64, 0, stream>>>(partials, dvec);
    emit_kern<<<NT / 4, 256, 0, stream>>>(x, ec, vw, dvec, emitw);
    chunk_kern<<<dim3(NSEQ, CHUNKS), 256, 0, stream>>>(S, emitw, Gc, Rc);
    combine_kern<<<NSEQ, 256, 0, stream>>>(Gc, Rc, sw, sb, out);
}

// Round 4
// 312.776 us; speedup vs baseline: 1.3539x; 1.3539x over previous
//
#include <hip/hip_runtime.h>
#include <hip/hip_bf16.h>
#include <stdint.h>

#define NT 16320      // 64 * 255
#define NTPAD 16384
#define KDIM 128      // padded from 100
#define NCOLS 4096    // K*K
#define NSEQ 64
#define TSTEPS 255
#define VOCAB 32000
#define EDIM 100
#define KST 64        // number of HMM states
#define CHUNKS 17
#define CLEN 15       // 17*15 = 255

typedef __attribute__((ext_vector_type(8))) short s8v;
typedef __attribute__((ext_vector_type(4))) float f4v;

__device__ __forceinline__ float bfhi(uint32_t u) { return __uint_as_float(u & 0xffff0000u); }
__device__ __forceinline__ float bflo(uint32_t u) { return __uint_as_float(u << 16); }

// async global->LDS, 16B per lane; lane i writes lds_base + i*16 (wave-uniform base)
__device__ __forceinline__ void load_lds16(const void* g, void* l) {
    __builtin_amdgcn_global_load_lds(
        (const __attribute__((address_space(1))) void*)(uintptr_t)g,
        (__attribute__((address_space(3))) void*)(uintptr_t)l,
        16, 0, 0);
}

// ---------------- prep A: gather embeddings -> bf16, K-pad to 128 -------------
__global__ void prep_a(const int* __restrict__ x, const float* __restrict__ emb,
                       __hip_bfloat16* __restrict__ A) {
    int m = blockIdx.x;          // 0..16383
    int e = threadIdx.x;         // 0..127
    float val = 0.f;
    if (m < NT) {
        int n = m / TSTEPS;
        int t = m - n * TSTEPS;
        int tok = x[n * 256 + t];
        if (e < EDIM) val = emb[(size_t)tok * EDIM + e];
    }
    A[(size_t)m * KDIM + e] = __float2bfloat16(val);
}

// ---------------- prep B: W_trans -> bf16, K-pad ------------------------------
__global__ void prep_b(const float* __restrict__ Wt, __hip_bfloat16* __restrict__ B) {
    int c = blockIdx.x;          // 0..4095
    int e = threadIdx.x;         // 0..127
    float val = (e < EDIM) ? Wt[(size_t)c * EDIM + e] : 0.f;
    B[(size_t)c * KDIM + e] = __float2bfloat16(val);
}

// ---------------- GEMM: 128x128 tile, global_load_lds staging, XOR swizzle ----
// LDS layout: row r of A (256B) lives at sA + r*256, 16B chunk c holds global
// chunk c ^ (r&7). ds_read side applies the same xor -> banks spread evenly.
__global__ __launch_bounds__(256) void gemm_kern(const __hip_bfloat16* __restrict__ A,
                                                 const __hip_bfloat16* __restrict__ B,
                                                 __hip_bfloat16* __restrict__ S) {
    int mblk = blockIdx.x;   // 0..127 (128 rows)
    int nblk = blockIdx.y;   // 0..31  (128 cols)
    int tid = threadIdx.x, wave = tid >> 6, lane = tid & 63;

    __shared__ __align__(16) char smem[65536];
    char* sA = smem;            // 128 rows * 256 B
    char* sB = smem + 32768;    // 128 cols * 256 B

    // ---- stage: wave w loads A rows [w*32,+32), B cols [w*32,+32) ----
    {
        int r0 = wave * 32;
        int l16 = lane & 15;      // chunk slot
        int rsub = lane >> 4;     // row within 4-row group
#pragma unroll
        for (int g = 0; g < 8; ++g) {
            int r = r0 + g * 4 + rsub;
            int chunk = l16 ^ (r & 7);
            const char* gp = (const char*)(A + (size_t)(mblk * 128 + r) * KDIM) + chunk * 16;
            load_lds16(gp, sA + (r0 + g * 4) * 256);
        }
#pragma unroll
        for (int g = 0; g < 8; ++g) {
            int c = r0 + g * 4 + rsub;
            int chunk = l16 ^ (c & 7);
            const char* gp = (const char*)(B + (size_t)(nblk * 128 + c) * KDIM) + chunk * 16;
            load_lds16(gp, sB + (r0 + g * 4) * 256);
        }
    }
    __syncthreads();

    // ---- compute: wave -> 64x64 subtile, 4x4 of 16x16x32 frags ----
    int wrow = (wave >> 1) * 64, wcol = (wave & 1) * 64;
    int l15 = lane & 15, g4 = lane >> 4;
    f4v acc[4][4] = {};
#pragma unroll
    for (int k32 = 0; k32 < 4; ++k32) {
        s8v af[4], bf[4];
#pragma unroll
        for (int mi = 0; mi < 4; ++mi) {
            int m = wrow + mi * 16 + l15;
            int chunk = (k32 * 4 + g4) ^ (m & 7);
            af[mi] = *(const s8v*)(sA + m * 256 + chunk * 16);
        }
#pragma unroll
        for (int ni = 0; ni < 4; ++ni) {
            int c = wcol + ni * 16 + l15;
            int chunk = (k32 * 4 + g4) ^ (c & 7);
            bf[ni] = *(const s8v*)(sB + c * 256 + chunk * 16);
        }
#pragma unroll
        for (int mi = 0; mi < 4; ++mi)
#pragma unroll
            for (int ni = 0; ni < 4; ++ni)
                acc[mi][ni] = __builtin_amdgcn_mfma_f32_16x16x32_bf16(af[mi], bf[ni], acc[mi][ni], 0, 0, 0);
    }
    __syncthreads();   // staging LDS dead; reuse for epilogue

    // ---- epilogue: per-wave 64x72 LDS round-trip, coalesced 64B-line stores --
    __hip_bfloat16* sW = (__hip_bfloat16*)(smem + wave * 9216);
#pragma unroll
    for (int mi = 0; mi < 4; ++mi)
#pragma unroll
        for (int ni = 0; ni < 4; ++ni)
#pragma unroll
            for (int r = 0; r < 4; ++r) {
                int row = mi * 16 + g4 * 4 + r;        // C/D: col=lane&15, row=(lane>>4)*4+r
                sW[row * 72 + ni * 16 + l15] = __float2bfloat16(acc[mi][ni][r]);
            }
    __syncthreads();
#pragma unroll
    for (int pass = 0; pass < 4; ++pass) {
        int r = pass * 16 + (lane >> 2);
        int q = lane & 3;
        int m = mblk * 128 + wrow + r;
        if (m < NT) {
            const uint4* src = (const uint4*)&sW[r * 72 + q * 16];
            uint4* dst = (uint4*)(S + (size_t)m * NCOLS + nblk * 128 + wcol + q * 16);
            dst[0] = src[0];
            dst[1] = src[1];
        }
    }
}

// ---------------- emission denominators: partial online-lse over vocab --------
__global__ __launch_bounds__(256) void dkern(const float* __restrict__ ec,
                                             const float* __restrict__ vw,
                                             float* __restrict__ partials) {
    __shared__ float ecT[64 * 64];
    int tid = threadIdx.x;
    for (int idx = tid; idx < 4096; idx += 256) {
        int k = idx >> 6, e = idx & 63;
        ecT[e * 64 + k] = ec[idx];
    }
    __syncthreads();
    int wave = tid >> 6, lane = tid & 63;
    int v0 = blockIdx.x * 125;
    float m = -1e30f, s = 0.f;
    for (int v = v0 + wave; v < v0 + 125; v += 4) {
        const float* row = vw + (size_t)v * 64;
        float acc = 0.f;
#pragma unroll
        for (int e = 0; e < 64; ++e) acc += ecT[e * 64 + lane] * row[e];
        float nm = fmaxf(m, acc);
        s = s * __expf(m - nm) + __expf(acc - nm);
        m = nm;
    }
    __shared__ float pm[4][64], ps[4][64];
    pm[wave][lane] = m; ps[wave][lane] = s;
    __syncthreads();
    if (tid < 64) {
        float M = pm[0][tid], Ssum = ps[0][tid];
#pragma unroll
        for (int w = 1; w < 4; ++w) {
            float m2 = pm[w][tid], s2 = ps[w][tid];
            float nm = fmaxf(M, m2);
            Ssum = Ssum * __expf(M - nm) + s2 * __expf(m2 - nm);
            M = nm;
        }
        partials[(blockIdx.x * 64 + tid) * 2]     = M;
        partials[(blockIdx.x * 64 + tid) * 2 + 1] = Ssum;
    }
}

__global__ void dreduce(const float* __restrict__ partials, float* __restrict__ d) {
    int k = threadIdx.x;   // 64 threads
    float M = -1e30f, S = 0.f;
    for (int b = 0; b < 256; ++b) {
        float m2 = partials[(b * 64 + k) * 2];
        float s2 = partials[(b * 64 + k) * 2 + 1];
        float nm = fmaxf(M, m2);
        S = S * __expf(M - nm) + s2 * __expf(m2 - nm);
        M = nm;
    }
    d[k] = M + __logf(S);
}

// ---------------- emissions for observed tokens -------------------------------
__global__ __launch_bounds__(256) void emit_kern(const int* __restrict__ x,
                                                 const float* __restrict__ ec,
                                                 const float* __restrict__ vw,
                                                 const float* __restrict__ d,
                                                 float* __restrict__ emit) {
    __shared__ float ecT[64 * 64];
    int tid = threadIdx.x;
    for (int idx = tid; idx < 4096; idx += 256) {
        int k = idx >> 6, e = idx & 63;
        ecT[e * 64 + k] = ec[idx];
    }
    __syncthreads();
    int wave = tid >> 6, lane = tid & 63;
    int nt = blockIdx.x * 4 + wave;      // grid = 4080 -> exactly 16320
    int n = nt / TSTEPS;
    int t = nt - n * TSTEPS;
    int tok = x[n * 256 + t + 1];
    const float* row = vw + (size_t)tok * 64;
    float acc = 0.f;
#pragma unroll
    for (int e = 0; e < 64; ++e) acc += ecT[e * 64 + lane] * row[e];
    emit[(size_t)nt * 64 + lane] = acc - d[lane];
}

// ---------------- chunk kernel: log-semiring product of 15 step-matrices ------
__global__ __launch_bounds__(256) void chunk_kern(const __hip_bfloat16* __restrict__ S,
                                                  const float* __restrict__ emitw,
                                                  __hip_bfloat16* __restrict__ Gout,
                                                  float* __restrict__ Rout) {
    int n = blockIdx.x, c = blockIdx.y;
    int tid = threadIdx.x, wave = tid >> 6, lane = tid & 63;

    __shared__ __align__(16) float sX[64 * 65];            // exp(S - rowmax), fp32
    __shared__ __align__(16) __hip_bfloat16 sE[64 * 72];   // E^T: sE[j*72+i] = E[i][j]
    __shared__ __align__(16) __hip_bfloat16 sG[64 * 72];   // Gexp: sG[a*72+i]
    __shared__ float sR[64];
    __shared__ float sRowInv[64];
    __shared__ float sEm[64];

    // init G = identity (exp-domain), r = 0
    for (int idx = tid; idx < 4096; idx += 256) {
        int a = idx >> 6, i = idx & 63;
        sG[a * 72 + i] = __float2bfloat16(a == i ? 1.f : 0.f);
    }
    if (tid < 64) sR[tid] = 0.f;
    __syncthreads();

    const __hip_bfloat16* Sn = S + ((size_t)(n * TSTEPS + c * CLEN)) * NCOLS;
    const float* em_n = emitw + (size_t)n * TSTEPS * 64 + (size_t)c * CLEN * 64;

    int i_a = tid >> 2, q = tid & 3;   // pass (a): row i_a, col strip q*16

    for (int tl = 0; tl < CLEN; ++tl) {
        // ---- (a) load S tile strip, rowmax/rowsum, write X = exp(S - rm) ----
        const uint4* sp = (const uint4*)(Sn + (size_t)tl * NCOLS + i_a * 64 + q * 16);
        uint4 r0 = sp[0], r1 = sp[1];
        float f[16];
        {
            const uint32_t* u = (const uint32_t*)&r0;
#pragma unroll
            for (int i = 0; i < 4; ++i) { f[2*i] = bflo(u[i]); f[2*i+1] = bfhi(u[i]); }
            const uint32_t* u2 = (const uint32_t*)&r1;
#pragma unroll
            for (int i = 0; i < 4; ++i) { f[8+2*i] = bflo(u2[i]); f[8+2*i+1] = bfhi(u2[i]); }
        }
        float m = f[0];
#pragma unroll
        for (int k = 1; k < 16; ++k) m = fmaxf(m, f[k]);
        m = fmaxf(m, __shfl_xor(m, 1, 64));
        m = fmaxf(m, __shfl_xor(m, 2, 64));
        float sig = 0.f;
        float xv[16];
#pragma unroll
        for (int k = 0; k < 16; ++k) { xv[k] = __expf(f[k] - m); sig += xv[k]; }
        sig += __shfl_xor(sig, 1, 64);
        sig += __shfl_xor(sig, 2, 64);
        float* xd = sX + i_a * 65 + q * 16;
#pragma unroll
        for (int k = 0; k < 16; ++k) xd[k] = xv[k];
        if (q == 0) sRowInv[i_a] = 1.0f / sig;
        if (tid < 64) sEm[tid] = __expf(em_n[tl * 64 + tid]);
        __syncthreads();

        // ---- (b) E^T[j][i] = X[i][j] * e^{em_j} / sigma_i, bf16 -------------
        {
            float emj = sEm[lane];
#pragma unroll
            for (int r = 0; r < 16; r += 2) {
                int i = wave * 16 + r;
                float v0 = sX[i * 65 + lane] * emj * sRowInv[i];
                float v1 = sX[(i + 1) * 65 + lane] * emj * sRowInv[i + 1];
                union { __hip_bfloat16 h[2]; uint32_t u; } p;
                p.h[0] = __float2bfloat16(v0);
                p.h[1] = __float2bfloat16(v1);
                *(uint32_t*)&sE[lane * 72 + i] = p.u;
            }
        }
        __syncthreads();

        // ---- (c) P = Gexp . E via MFMA: wave handles rows [16w,16w+16) ------
        f4v acc[4] = {};
        int arow = wave * 16 + (lane & 15);
        int koff = (lane >> 4) * 8;
#pragma unroll
        for (int kk = 0; kk < 2; ++kk) {
            s8v a = *(const s8v*)(sG + arow * 72 + kk * 32 + koff);
#pragma unroll
            for (int jt = 0; jt < 4; ++jt) {
                s8v b = *(const s8v*)(sE + (jt * 16 + (lane & 15)) * 72 + kk * 32 + koff);
                acc[jt] = __builtin_amdgcn_mfma_f32_16x16x32_bf16(a, b, acc[jt], 0, 0, 0);
            }
        }

        // ---- (d) rowmax-normalize P -> Gexp, r += log(rowmax) ---------------
        float rmx[4];
#pragma unroll
        for (int rr = 0; rr < 4; ++rr) {
            float mm = acc[0][rr];
#pragma unroll
            for (int jt = 1; jt < 4; ++jt) mm = fmaxf(mm, acc[jt][rr]);
            mm = fmaxf(mm, __shfl_xor(mm, 1, 64));
            mm = fmaxf(mm, __shfl_xor(mm, 2, 64));
            mm = fmaxf(mm, __shfl_xor(mm, 4, 64));
            mm = fmaxf(mm, __shfl_xor(mm, 8, 64));
            rmx[rr] = fmaxf(mm, 1e-35f);
        }
#pragma unroll
        for (int rr = 0; rr < 4; ++rr) {
            int row = wave * 16 + (lane >> 4) * 4 + rr;
            float inv = 1.0f / rmx[rr];
#pragma unroll
            for (int jt = 0; jt < 4; ++jt)
                sG[row * 72 + jt * 16 + (lane & 15)] = __float2bfloat16(acc[jt][rr] * inv);
        }
        if ((lane & 15) == 0) {
#pragma unroll
            for (int rr = 0; rr < 4; ++rr) {
                int row = wave * 16 + (lane >> 4) * 4 + rr;
                sR[row] += __logf(rmx[rr]);
            }
        }
        __syncthreads();
    }

    // ---- output: compact Gexp + row scales ----
    __hip_bfloat16* go = Gout + ((size_t)(n * CHUNKS + c)) * 4096;
    for (int idx = tid; idx < 4096; idx += 256) {
        int a = idx >> 6, i = idx & 63;
        go[idx] = sG[a * 72 + i];
    }
    if (tid < 64) Rout[(size_t)(n * CHUNKS + c) * 64 + tid] = sR[tid];
}

// ---------------- combine: alpha0 through 17 chunk matrices -------------------
__global__ __launch_bounds__(256) void combine_kern(const __hip_bfloat16* __restrict__ G,
                                                    const float* __restrict__ R,
                                                    const float* __restrict__ sw,
                                                    const float* __restrict__ sb,
                                                    float* __restrict__ out) {
    int n = blockIdx.x;
    int tid = threadIdx.x, wave = tid >> 6, lane = tid & 63;
    __shared__ float sA2[64], sV[64], pw[4][64];
    __shared__ float sMx;

    if (tid < 64) {
        float v = sw[tid] + sb[tid];
        float m = v;
        for (int off = 1; off < 64; off <<= 1) m = fmaxf(m, __shfl_xor(m, off, 64));
        float s = __expf(v - m);
        for (int off = 1; off < 64; off <<= 1) s += __shfl_xor(s, off, 64);
        sA2[tid] = v - (m + __logf(s));
    }
    __syncthreads();

    for (int c = 0; c < CHUNKS; ++c) {
        const __hip_bfloat16* Gc = G + ((size_t)(n * CHUNKS + c)) * 4096;
        const float* Rc = R + (size_t)(n * CHUNKS + c) * 64;
        if (tid < 64) {
            float t = sA2[tid] + Rc[tid];
            float m = t;
            for (int off = 1; off < 64; off <<= 1) m = fmaxf(m, __shfl_xor(m, off, 64));
            sV[tid] = __expf(t - m);
            if (tid == 0) sMx = m;
        }
        __syncthreads();
        float part = 0.f;
        int i0 = wave * 16;
#pragma unroll
        for (int r = 0; r < 16; ++r)
            part += sV[i0 + r] * __bfloat162float(Gc[(i0 + r) * 64 + lane]);
        pw[wave][lane] = part;
        __syncthreads();
        if (tid < 64) {
            float w = pw[0][tid] + pw[1][tid] + pw[2][tid] + pw[3][tid];
            sA2[tid] = sMx + __logf(w);
        }
        __syncthreads();
    }

    if (tid < 64) {
        float v = sA2[tid];
        float m = v;
        for (int off = 1; off < 64; off <<= 1) m = fmaxf(m, __shfl_xor(m, off, 64));
        float s = __expf(v - m);
        for (int off = 1; off < 64; off <<= 1) s += __shfl_xor(s, off, 64);
        if (tid == 0) atomicAdd(out, -(m + __logf(s)) * (1.0f / 64.0f));
    }
}

extern "C" void kernel_launch(void* const* d_in, const int* in_sizes, int n_in,
                              void* d_out, int out_size, void* d_ws, size_t ws_size,
                              hipStream_t stream) {
    const int*   x   = (const int*)d_in[0];
    const float* emb = (const float*)d_in[1];
    const float* Wt  = (const float*)d_in[2];
    const float* sw  = (const float*)d_in[3];
    const float* sb  = (const float*)d_in[4];
    const float* ec  = (const float*)d_in[5];
    const float* vw  = (const float*)d_in[6];
    float* out = (float*)d_out;
    char* ws = (char*)d_ws;

    __hip_bfloat16* S  = (__hip_bfloat16*)ws;                          // 133,693,440 B (uses 16384 rows pad)
    __hip_bfloat16* A  = (__hip_bfloat16*)(ws + 134217728ull);         //   4,194,304 B
    __hip_bfloat16* B  = (__hip_bfloat16*)(ws + 138412032ull);         //   1,048,576 B
    float* emitw       = (float*)(ws + 139460608ull);                  //   4,177,920 B
    float* dvec        = (float*)(ws + 143638528ull);                  //       1,024 B
    float* partials    = (float*)(ws + 143639552ull);                  //     131,072 B
    __hip_bfloat16* Gc = (__hip_bfloat16*)(ws + 143770624ull);         //   8,912,896 B
    float* Rc          = (float*)(ws + 152683520ull);                  //     278,528 B
                                                                       // end 152,962,048

    hipMemsetAsync(out, 0, sizeof(float), stream);

    prep_a<<<NTPAD, 128, 0, stream>>>(x, emb, A);
    prep_b<<<NCOLS, 128, 0, stream>>>(Wt, B);
    gemm_kern<<<dim3(NTPAD / 128, NCOLS / 128), 256, 0, stream>>>(A, B, S);
    dkern<<<256, 256, 0, stream>>>(ec, vw, partials);
    dreduce<<<1, 64, 0, stream>>>(partials, dvec);
    emit_kern<<<NT / 4, 256, 0, stream>>>(x, ec, vw, dvec, emitw);
    chunk_kern<<<dim3(NSEQ, CHUNKS), 256, 0, stream>>>(S, emitw, Gc, Rc);
    combine_kern<<<NSEQ, 256, 0, stream>>>(Gc, Rc, sw, sb, out);
}

// Round 5
// 301.039 us; speedup vs baseline: 1.4066x; 1.0390x over previous
//
#include <hip/hip_runtime.h>
#include <hip/hip_bf16.h>
#include <stdint.h>

#define NT 16320      // 64 * 255
#define NTPAD 16384
#define KDIM 128      // padded from 100
#define NCOLS 4096    // K*K
#define NSEQ 64
#define TSTEPS 255
#define VOCAB 32000
#define EDIM 100
#define KST 64        // number of HMM states
#define CHUNKS 17
#define CLEN 15       // 17*15 = 255

typedef __attribute__((ext_vector_type(8))) short s8v;
typedef __attribute__((ext_vector_type(4))) float f4v;

__device__ __forceinline__ float bfhi(uint32_t u) { return __uint_as_float(u & 0xffff0000u); }
__device__ __forceinline__ float bflo(uint32_t u) { return __uint_as_float(u << 16); }

// async global->LDS, 16B per lane; lane i writes lds_base + i*16 (wave-uniform base)
__device__ __forceinline__ void load_lds16(const void* g, void* l) {
    __builtin_amdgcn_global_load_lds(
        (const __attribute__((address_space(1))) void*)(uintptr_t)g,
        (__attribute__((address_space(3))) void*)(uintptr_t)l,
        16, 0, 0);
}

// ---------------- prep A: gather embeddings -> bf16, K-pad to 128 -------------
__global__ void prep_a(const int* __restrict__ x, const float* __restrict__ emb,
                       __hip_bfloat16* __restrict__ A) {
    int m = blockIdx.x;          // 0..16383
    int e = threadIdx.x;         // 0..127
    float val = 0.f;
    if (m < NT) {
        int n = m / TSTEPS;
        int t = m - n * TSTEPS;
        int tok = x[n * 256 + t];
        if (e < EDIM) val = emb[(size_t)tok * EDIM + e];
    }
    A[(size_t)m * KDIM + e] = __float2bfloat16(val);
}

// ---------------- prep B: W_trans -> bf16, K-pad ------------------------------
__global__ void prep_b(const float* __restrict__ Wt, __hip_bfloat16* __restrict__ B) {
    int c = blockIdx.x;          // 0..4095
    int e = threadIdx.x;         // 0..127
    float val = (e < EDIM) ? Wt[(size_t)c * EDIM + e] : 0.f;
    B[(size_t)c * KDIM + e] = __float2bfloat16(val);
}

// ---------------- GEMM: 128x128 tile, global_load_lds staging, XOR swizzle ----
__global__ __launch_bounds__(256) void gemm_kern(const __hip_bfloat16* __restrict__ A,
                                                 const __hip_bfloat16* __restrict__ B,
                                                 __hip_bfloat16* __restrict__ S) {
    int mblk = blockIdx.x;   // 0..127 (128 rows)
    int nblk = blockIdx.y;   // 0..31  (128 cols)
    int tid = threadIdx.x, wave = tid >> 6, lane = tid & 63;

    __shared__ __align__(16) char smem[65536];
    char* sA = smem;            // 128 rows * 256 B
    char* sB = smem + 32768;    // 128 cols * 256 B

    // ---- stage: wave w loads A rows [w*32,+32), B cols [w*32,+32) ----
    {
        int r0 = wave * 32;
        int l16 = lane & 15;      // chunk slot
        int rsub = lane >> 4;     // row within 4-row group
#pragma unroll
        for (int g = 0; g < 8; ++g) {
            int r = r0 + g * 4 + rsub;
            int chunk = l16 ^ (r & 7);
            const char* gp = (const char*)(A + (size_t)(mblk * 128 + r) * KDIM) + chunk * 16;
            load_lds16(gp, sA + (r0 + g * 4) * 256);
        }
#pragma unroll
        for (int g = 0; g < 8; ++g) {
            int c = r0 + g * 4 + rsub;
            int chunk = l16 ^ (c & 7);
            const char* gp = (const char*)(B + (size_t)(nblk * 128 + c) * KDIM) + chunk * 16;
            load_lds16(gp, sB + (r0 + g * 4) * 256);
        }
    }
    __syncthreads();

    // ---- compute: wave -> 64x64 subtile, 4x4 of 16x16x32 frags ----
    int wrow = (wave >> 1) * 64, wcol = (wave & 1) * 64;
    int l15 = lane & 15, g4 = lane >> 4;
    f4v acc[4][4] = {};
#pragma unroll
    for (int k32 = 0; k32 < 4; ++k32) {
        s8v af[4], bf[4];
#pragma unroll
        for (int mi = 0; mi < 4; ++mi) {
            int m = wrow + mi * 16 + l15;
            int chunk = (k32 * 4 + g4) ^ (m & 7);
            af[mi] = *(const s8v*)(sA + m * 256 + chunk * 16);
        }
#pragma unroll
        for (int ni = 0; ni < 4; ++ni) {
            int c = wcol + ni * 16 + l15;
            int chunk = (k32 * 4 + g4) ^ (c & 7);
            bf[ni] = *(const s8v*)(sB + c * 256 + chunk * 16);
        }
#pragma unroll
        for (int mi = 0; mi < 4; ++mi)
#pragma unroll
            for (int ni = 0; ni < 4; ++ni)
                acc[mi][ni] = __builtin_amdgcn_mfma_f32_16x16x32_bf16(af[mi], bf[ni], acc[mi][ni], 0, 0, 0);
    }
    __syncthreads();   // staging LDS dead; reuse for epilogue

    // ---- epilogue: per-wave 64x72 LDS round-trip, coalesced 64B-line stores --
    __hip_bfloat16* sW = (__hip_bfloat16*)(smem + wave * 9216);
#pragma unroll
    for (int mi = 0; mi < 4; ++mi)
#pragma unroll
        for (int ni = 0; ni < 4; ++ni)
#pragma unroll
            for (int r = 0; r < 4; ++r) {
                int row = mi * 16 + g4 * 4 + r;        // C/D: col=lane&15, row=(lane>>4)*4+r
                sW[row * 72 + ni * 16 + l15] = __float2bfloat16(acc[mi][ni][r]);
            }
    __syncthreads();
#pragma unroll
    for (int pass = 0; pass < 4; ++pass) {
        int r = pass * 16 + (lane >> 2);
        int q = lane & 3;
        int m = mblk * 128 + wrow + r;
        if (m < NT) {
            const uint4* src = (const uint4*)&sW[r * 72 + q * 16];
            uint4* dst = (uint4*)(S + (size_t)m * NCOLS + nblk * 128 + wcol + q * 16);
            dst[0] = src[0];
            dst[1] = src[1];
        }
    }
}

// ---------------- emission denominators: partial online-lse over vocab --------
__global__ __launch_bounds__(256) void dkern(const float* __restrict__ ec,
                                             const float* __restrict__ vw,
                                             float* __restrict__ partials) {
    __shared__ float ecT[64 * 64];
    int tid = threadIdx.x;
    for (int idx = tid; idx < 4096; idx += 256) {
        int k = idx >> 6, e = idx & 63;
        ecT[e * 64 + k] = ec[idx];
    }
    __syncthreads();
    int wave = tid >> 6, lane = tid & 63;
    int v0 = blockIdx.x * 125;
    float m = -1e30f, s = 0.f;
    for (int v = v0 + wave; v < v0 + 125; v += 4) {
        const float* row = vw + (size_t)v * 64;
        float acc = 0.f;
#pragma unroll
        for (int e = 0; e < 64; ++e) acc += ecT[e * 64 + lane] * row[e];
        float nm = fmaxf(m, acc);
        s = s * __expf(m - nm) + __expf(acc - nm);
        m = nm;
    }
    __shared__ float pm[4][64], ps[4][64];
    pm[wave][lane] = m; ps[wave][lane] = s;
    __syncthreads();
    if (tid < 64) {
        float M = pm[0][tid], Ssum = ps[0][tid];
#pragma unroll
        for (int w = 1; w < 4; ++w) {
            float m2 = pm[w][tid], s2 = ps[w][tid];
            float nm = fmaxf(M, m2);
            Ssum = Ssum * __expf(M - nm) + s2 * __expf(m2 - nm);
            M = nm;
        }
        partials[(blockIdx.x * 64 + tid) * 2]     = M;
        partials[(blockIdx.x * 64 + tid) * 2 + 1] = Ssum;
    }
}

__global__ __launch_bounds__(256) void dreduce(const float* __restrict__ partials,
                                               float* __restrict__ d) {
    __shared__ float pm[4][64], ps[4][64];
    int k = threadIdx.x & 63, part = threadIdx.x >> 6;
    float M = -1e30f, S = 0.f;
    for (int b = part; b < 256; b += 4) {
        float m2 = partials[(b * 64 + k) * 2];
        float s2 = partials[(b * 64 + k) * 2 + 1];
        float nm = fmaxf(M, m2);
        S = S * __expf(M - nm) + s2 * __expf(m2 - nm);
        M = nm;
    }
    pm[part][k] = M; ps[part][k] = S;
    __syncthreads();
    if (threadIdx.x < 64) {
        float Mm = pm[0][k], Ss = ps[0][k];
#pragma unroll
        for (int w = 1; w < 4; ++w) {
            float m2 = pm[w][k], s2 = ps[w][k];
            float nm = fmaxf(Mm, m2);
            Ss = Ss * __expf(Mm - nm) + s2 * __expf(m2 - nm);
            Mm = nm;
        }
        d[k] = Mm + __logf(Ss);
    }
}

// ---------------- emissions for observed tokens -------------------------------
__global__ __launch_bounds__(256) void emit_kern(const int* __restrict__ x,
                                                 const float* __restrict__ ec,
                                                 const float* __restrict__ vw,
                                                 const float* __restrict__ d,
                                                 float* __restrict__ emit) {
    __shared__ float ecT[64 * 64];
    int tid = threadIdx.x;
    for (int idx = tid; idx < 4096; idx += 256) {
        int k = idx >> 6, e = idx & 63;
        ecT[e * 64 + k] = ec[idx];
    }
    __syncthreads();
    int wave = tid >> 6, lane = tid & 63;
    int nt = blockIdx.x * 4 + wave;      // grid = 4080 -> exactly 16320
    int n = nt / TSTEPS;
    int t = nt - n * TSTEPS;
    int tok = x[n * 256 + t + 1];
    const float* row = vw + (size_t)tok * 64;
    float acc = 0.f;
#pragma unroll
    for (int e = 0; e < 64; ++e) acc += ecT[e * 64 + lane] * row[e];
    emit[(size_t)nt * 64 + lane] = acc - d[lane];
}

// ---------------- chunk kernel: log-semiring product of 15 step-matrices ------
// Thread (p = tid>>3, q8 = tid&7) owns T-rows i0=2p,i0+1, cols [q8*8,+8).
// E^T stored bf16 in sE with 16B-chunk XOR swizzle: chunk = (i>>3)^(j&7).
// Per step: 2 barriers; S strip + emissions register-prefetched.
__global__ __launch_bounds__(256) void chunk_kern(const __hip_bfloat16* __restrict__ S,
                                                  const float* __restrict__ emitw,
                                                  __hip_bfloat16* __restrict__ Gout,
                                                  float* __restrict__ Rout) {
    int n = blockIdx.x, c = blockIdx.y;
    int tid = threadIdx.x, wave = tid >> 6, lane = tid & 63;
    int p = tid >> 3, q8 = tid & 7;
    int i0 = p * 2;

    __shared__ __align__(16) char sE[64 * 128];            // E^T, swizzled, 8 KB
    __shared__ __align__(16) __hip_bfloat16 sG[64 * 72];   // Gexp: sG[a*72+i]
    __shared__ float sR[64];

    // init G = identity (exp-domain), r = 0
    for (int idx = tid; idx < 4096; idx += 256) {
        int a = idx >> 6, i = idx & 63;
        sG[a * 72 + i] = __float2bfloat16(a == i ? 1.f : 0.f);
    }
    if (tid < 64) sR[tid] = 0.f;
    __syncthreads();

    const __hip_bfloat16* Sn = S + ((size_t)(n * TSTEPS + c * CLEN)) * NCOLS;
    const float* em_n = emitw + (size_t)n * TSTEPS * 64 + (size_t)c * CLEN * 64;

    // prefetch step 0
    uint4 u0 = *(const uint4*)(Sn + i0 * 64 + q8 * 8);
    uint4 u1 = *(const uint4*)(Sn + (i0 + 1) * 64 + q8 * 8);
    float4 e0 = *(const float4*)(em_n + q8 * 8);
    float4 e1 = *(const float4*)(em_n + q8 * 8 + 4);

    int l15 = lane & 15, g4 = lane >> 4;
    int sw = q8 & 1;   // 1-bit write-order twist for bank spread

    for (int tl = 0; tl < CLEN; ++tl) {
        // unpack current prefetched values
        float f0[8], f1[8], ee[8];
        {
            const uint32_t* u = (const uint32_t*)&u0;
#pragma unroll
            for (int i = 0; i < 4; ++i) { f0[2*i] = bflo(u[i]); f0[2*i+1] = bfhi(u[i]); }
            const uint32_t* v = (const uint32_t*)&u1;
#pragma unroll
            for (int i = 0; i < 4; ++i) { f1[2*i] = bflo(v[i]); f1[2*i+1] = bfhi(v[i]); }
        }
        ee[0] = e0.x; ee[1] = e0.y; ee[2] = e0.z; ee[3] = e0.w;
        ee[4] = e1.x; ee[5] = e1.y; ee[6] = e1.z; ee[7] = e1.w;

        // issue next step's prefetch
        if (tl + 1 < CLEN) {
            const __hip_bfloat16* Sn2 = Sn + (size_t)(tl + 1) * NCOLS;
            u0 = *(const uint4*)(Sn2 + i0 * 64 + q8 * 8);
            u1 = *(const uint4*)(Sn2 + (i0 + 1) * 64 + q8 * 8);
            const float* em2 = em_n + (tl + 1) * 64 + q8 * 8;
            e0 = *(const float4*)(em2);
            e1 = *(const float4*)(em2 + 4);
        }

        // row reductions (over q8 lanes, xor 1/2/4)
        float m0 = f0[0], m1 = f1[0];
#pragma unroll
        for (int k = 1; k < 8; ++k) { m0 = fmaxf(m0, f0[k]); m1 = fmaxf(m1, f1[k]); }
#pragma unroll
        for (int off = 1; off <= 4; off <<= 1) {
            m0 = fmaxf(m0, __shfl_xor(m0, off, 64));
            m1 = fmaxf(m1, __shfl_xor(m1, off, 64));
        }
        float x0[8], x1[8], s0 = 0.f, s1 = 0.f;
#pragma unroll
        for (int k = 0; k < 8; ++k) {
            x0[k] = __expf(f0[k] - m0); s0 += x0[k];
            x1[k] = __expf(f1[k] - m1); s1 += x1[k];
        }
#pragma unroll
        for (int off = 1; off <= 4; off <<= 1) {
            s0 += __shfl_xor(s0, off, 64);
            s1 += __shfl_xor(s1, off, 64);
        }
        float inv0 = 1.0f / s0, inv1 = 1.0f / s1;

        // w = x * exp(em) * inv  (E entries)
        float w0[8], w1[8];
#pragma unroll
        for (int k = 0; k < 8; ++k) {
            float eme = __expf(ee[k]);
            w0[k] = x0[k] * eme * inv0;
            w1[k] = x1[k] * eme * inv1;
        }

        // write E^T i-pairs as b32, swizzled chunks; pairwise order twist
        {
            int pc = p >> 2;     // i0>>3
            int pb = (p & 3) * 4;
#pragma unroll
            for (int l = 0; l < 8; l += 2) {
                float a0 = w0[l], b0 = w0[l + 1];
                float a1 = w1[l], b1 = w1[l + 1];
                float va0 = sw ? b0 : a0, vb0 = sw ? a0 : b0;
                float va1 = sw ? b1 : a1, vb1 = sw ? a1 : b1;
                int jla = l ^ sw, jlb = (l + 1) ^ sw;
                union { __hip_bfloat16 h[2]; uint32_t u; } pa, pb2;
                pa.h[0] = __float2bfloat16(va0); pa.h[1] = __float2bfloat16(va1);
                pb2.h[0] = __float2bfloat16(vb0); pb2.h[1] = __float2bfloat16(vb1);
                int jga = q8 * 8 + jla, jgb = q8 * 8 + jlb;
                *(uint32_t*)(sE + jga * 128 + ((pc ^ jla) * 16) + pb) = pa.u;
                *(uint32_t*)(sE + jgb * 128 + ((pc ^ jlb) * 16) + pb) = pb2.u;
            }
        }
        __syncthreads();   // sE visible

        // ---- P = Gexp . E via MFMA: wave handles rows [16w,16w+16) ------
        f4v acc[4] = {};
        int arow = wave * 16 + l15;
#pragma unroll
        for (int kk = 0; kk < 2; ++kk) {
            s8v a = *(const s8v*)(sG + arow * 72 + kk * 32 + g4 * 8);
#pragma unroll
            for (int jt = 0; jt < 4; ++jt) {
                int j = jt * 16 + l15;
                s8v b = *(const s8v*)(sE + j * 128 + (((kk * 4 + g4) ^ (l15 & 7)) * 16));
                acc[jt] = __builtin_amdgcn_mfma_f32_16x16x32_bf16(a, b, acc[jt], 0, 0, 0);
            }
        }

        // ---- rowmax-normalize P -> Gexp, r += log(rowmax) ---------------
        float rmx[4];
#pragma unroll
        for (int rr = 0; rr < 4; ++rr) {
            float mm = acc[0][rr];
#pragma unroll
            for (int jt = 1; jt < 4; ++jt) mm = fmaxf(mm, acc[jt][rr]);
            mm = fmaxf(mm, __shfl_xor(mm, 1, 64));
            mm = fmaxf(mm, __shfl_xor(mm, 2, 64));
            mm = fmaxf(mm, __shfl_xor(mm, 4, 64));
            mm = fmaxf(mm, __shfl_xor(mm, 8, 64));
            rmx[rr] = fmaxf(mm, 1e-35f);
        }
#pragma unroll
        for (int rr = 0; rr < 4; ++rr) {
            int row = wave * 16 + g4 * 4 + rr;
            float inv = 1.0f / rmx[rr];
#pragma unroll
            for (int jt = 0; jt < 4; ++jt)
                sG[row * 72 + jt * 16 + l15] = __float2bfloat16(acc[jt][rr] * inv);
        }
        if (l15 == 0) {
#pragma unroll
            for (int rr = 0; rr < 4; ++rr) {
                int row = wave * 16 + g4 * 4 + rr;
                sR[row] += __logf(rmx[rr]);
            }
        }
        __syncthreads();   // sE reads done; next step may overwrite
    }

    // ---- output: compact Gexp + row scales ----
    __hip_bfloat16* go = Gout + ((size_t)(n * CHUNKS + c)) * 4096;
    for (int idx = tid; idx < 4096; idx += 256) {
        int a = idx >> 6, i = idx & 63;
        go[idx] = sG[a * 72 + i];
    }
    if (tid < 64) Rout[(size_t)(n * CHUNKS + c) * 64 + tid] = sR[tid];
}

// ---------------- combine: alpha0 through 17 chunk matrices -------------------
__global__ __launch_bounds__(256) void combine_kern(const __hip_bfloat16* __restrict__ G,
                                                    const float* __restrict__ R,
                                                    const float* __restrict__ sw,
                                                    const float* __restrict__ sb,
                                                    float* __restrict__ out) {
    int n = blockIdx.x;
    int tid = threadIdx.x, wave = tid >> 6, lane = tid & 63;
    __shared__ float sA2[64], sV[64], pw[4][64];
    __shared__ float sMx;

    if (tid < 64) {
        float v = sw[tid] + sb[tid];
        float m = v;
        for (int off = 1; off < 64; off <<= 1) m = fmaxf(m, __shfl_xor(m, off, 64));
        float s = __expf(v - m);
        for (int off = 1; off < 64; off <<= 1) s += __shfl_xor(s, off, 64);
        sA2[tid] = v - (m + __logf(s));
    }
    __syncthreads();

    for (int c = 0; c < CHUNKS; ++c) {
        const __hip_bfloat16* Gc = G + ((size_t)(n * CHUNKS + c)) * 4096;
        const float* Rc = R + (size_t)(n * CHUNKS + c) * 64;
        if (tid < 64) {
            float t = sA2[tid] + Rc[tid];
            float m = t;
            for (int off = 1; off < 64; off <<= 1) m = fmaxf(m, __shfl_xor(m, off, 64));
            sV[tid] = __expf(t - m);
            if (tid == 0) sMx = m;
        }
        __syncthreads();
        float part = 0.f;
        int i0 = wave * 16;
#pragma unroll
        for (int r = 0; r < 16; ++r)
            part += sV[i0 + r] * __bfloat162float(Gc[(i0 + r) * 64 + lane]);
        pw[wave][lane] = part;
        __syncthreads();
        if (tid < 64) {
            float w = pw[0][tid] + pw[1][tid] + pw[2][tid] + pw[3][tid];
            sA2[tid] = sMx + __logf(w);
        }
        __syncthreads();
    }

    if (tid < 64) {
        float v = sA2[tid];
        float m = v;
        for (int off = 1; off < 64; off <<= 1) m = fmaxf(m, __shfl_xor(m, off, 64));
        float s = __expf(v - m);
        for (int off = 1; off < 64; off <<= 1) s += __shfl_xor(s, off, 64);
        if (tid == 0) atomicAdd(out, -(m + __logf(s)) * (1.0f / 64.0f));
    }
}

extern "C" void kernel_launch(void* const* d_in, const int* in_sizes, int n_in,
                              void* d_out, int out_size, void* d_ws, size_t ws_size,
                              hipStream_t stream) {
    const int*   x   = (const int*)d_in[0];
    const float* emb = (const float*)d_in[1];
    const float* Wt  = (const float*)d_in[2];
    const float* sw  = (const float*)d_in[3];
    const float* sb  = (const float*)d_in[4];
    const float* ec  = (const float*)d_in[5];
    const float* vw  = (const float*)d_in[6];
    float* out = (float*)d_out;
    char* ws = (char*)d_ws;

    __hip_bfloat16* S  = (__hip_bfloat16*)ws;                          // 134,217,728 B (16384 rows)
    __hip_bfloat16* A  = (__hip_bfloat16*)(ws + 134217728ull);         //   4,194,304 B
    __hip_bfloat16* B  = (__hip_bfloat16*)(ws + 138412032ull);         //   1,048,576 B
    float* emitw       = (float*)(ws + 139460608ull);                  //   4,177,920 B
    float* dvec        = (float*)(ws + 143638528ull);                  //       1,024 B
    float* partials    = (float*)(ws + 143639552ull);                  //     131,072 B
    __hip_bfloat16* Gc = (__hip_bfloat16*)(ws + 143770624ull);         //   8,912,896 B
    float* Rc          = (float*)(ws + 152683520ull);                  //     278,528 B
                                                                       // end 152,962,048

    hipMemsetAsync(out, 0, sizeof(float), stream);

    prep_a<<<NTPAD, 128, 0, stream>>>(x, emb, A);
    prep_b<<<NCOLS, 128, 0, stream>>>(Wt, B);
    gemm_kern<<<dim3(NTPAD / 128, NCOLS / 128), 256, 0, stream>>>(A, B, S);
    dkern<<<256, 256, 0, stream>>>(ec, vw, partials);
    dreduce<<<1, 256, 0, stream>>>(partials, dvec);
    emit_kern<<<NT / 4, 256, 0, stream>>>(x, ec, vw, dvec, emitw);
    chunk_kern<<<dim3(NSEQ, CHUNKS), 256, 0, stream>>>(S, emitw, Gc, Rc);
    combine_kern<<<NSEQ, 256, 0, stream>>>(Gc, Rc, sw, sb, out);
}

// Round 6
// 286.161 us; speedup vs baseline: 1.4798x; 1.0520x over previous
//
#include <hip/hip_runtime.h>
#include <hip/hip_bf16.h>
#include <stdint.h>

#define NT 16320      // 64 * 255
#define NTPAD 16384
#define KDIM 128      // padded from 100
#define NCOLS 4096    // K*K
#define NSEQ 64
#define TSTEPS 255
#define VOCAB 32000
#define EDIM 100
#define KST 64        // number of HMM states
#define CHUNKS 17
#define CLEN 15       // 17*15 = 255

typedef __attribute__((ext_vector_type(8))) short s8v;
typedef __attribute__((ext_vector_type(4))) float f4v;

__device__ __forceinline__ float bfhi(uint32_t u) { return __uint_as_float(u & 0xffff0000u); }
__device__ __forceinline__ float bflo(uint32_t u) { return __uint_as_float(u << 16); }

// async global->LDS, 16B per lane; lane i writes lds_base + i*16 (wave-uniform base)
__device__ __forceinline__ void load_lds16(const void* g, void* l) {
    __builtin_amdgcn_global_load_lds(
        (const __attribute__((address_space(1))) void*)(uintptr_t)g,
        (__attribute__((address_space(3))) void*)(uintptr_t)l,
        16, 0, 0);
}

// ---------------- prep A: gather embeddings -> bf16, K-pad to 128 -------------
__global__ void prep_a(const int* __restrict__ x, const float* __restrict__ emb,
                       __hip_bfloat16* __restrict__ A) {
    int m = blockIdx.x;          // 0..16383
    int e = threadIdx.x;         // 0..127
    float val = 0.f;
    if (m < NT) {
        int n = m / TSTEPS;
        int t = m - n * TSTEPS;
        int tok = x[n * 256 + t];
        if (e < EDIM) val = emb[(size_t)tok * EDIM + e];
    }
    A[(size_t)m * KDIM + e] = __float2bfloat16(val);
}

// ---------------- prep B: W_trans -> bf16, K-pad ------------------------------
__global__ void prep_b(const float* __restrict__ Wt, __hip_bfloat16* __restrict__ B) {
    int c = blockIdx.x;          // 0..4095
    int e = threadIdx.x;         // 0..127
    float val = (e < EDIM) ? Wt[(size_t)c * EDIM + e] : 0.f;
    B[(size_t)c * KDIM + e] = __float2bfloat16(val);
}

// ---------------- GEMM + fused softmax*emission -> E  -------------------------
// S[m][c] = A[m]·B[c]; per (m, i): E[m][i*64+j] = softmax_j(S) * expem[m][j].
// Wave's 64-col strip = one full i row -> softmax entirely in-wave.
__global__ __launch_bounds__(256) void gemm_kern(const __hip_bfloat16* __restrict__ A,
                                                 const __hip_bfloat16* __restrict__ B,
                                                 const float* __restrict__ emX,
                                                 __hip_bfloat16* __restrict__ Eg) {
    int mblk = blockIdx.x;   // 0..127
    int nblk = blockIdx.y;   // 0..31
    int tid = threadIdx.x, wave = tid >> 6, lane = tid & 63;

    __shared__ __align__(16) char smem[65536];
    char* sA = smem;            // 128 rows * 256 B
    char* sB = smem + 32768;    // 128 cols * 256 B

    // ---- stage: wave w loads A rows [w*32,+32), B cols [w*32,+32) ----
    {
        int r0 = wave * 32;
        int l16 = lane & 15;
        int rsub = lane >> 4;
#pragma unroll
        for (int g = 0; g < 8; ++g) {
            int r = r0 + g * 4 + rsub;
            int chunk = l16 ^ (r & 7);
            const char* gp = (const char*)(A + (size_t)(mblk * 128 + r) * KDIM) + chunk * 16;
            load_lds16(gp, sA + (r0 + g * 4) * 256);
        }
#pragma unroll
        for (int g = 0; g < 8; ++g) {
            int c = r0 + g * 4 + rsub;
            int chunk = l16 ^ (c & 7);
            const char* gp = (const char*)(B + (size_t)(nblk * 128 + c) * KDIM) + chunk * 16;
            load_lds16(gp, sB + (r0 + g * 4) * 256);
        }
    }
    __syncthreads();

    // ---- compute: wave -> 64x64 subtile (full j range for one i) ----
    int wrow = (wave >> 1) * 64, wcol = (wave & 1) * 64;
    int l15 = lane & 15, g4 = lane >> 4;
    f4v acc[4][4] = {};
#pragma unroll
    for (int k32 = 0; k32 < 4; ++k32) {
        s8v af[4], bf[4];
#pragma unroll
        for (int mi = 0; mi < 4; ++mi) {
            int m = wrow + mi * 16 + l15;
            int chunk = (k32 * 4 + g4) ^ (m & 7);
            af[mi] = *(const s8v*)(sA + m * 256 + chunk * 16);
        }
#pragma unroll
        for (int ni = 0; ni < 4; ++ni) {
            int c = wcol + ni * 16 + l15;
            int chunk = (k32 * 4 + g4) ^ (c & 7);
            bf[ni] = *(const s8v*)(sB + c * 256 + chunk * 16);
        }
#pragma unroll
        for (int mi = 0; mi < 4; ++mi)
#pragma unroll
            for (int ni = 0; ni < 4; ++ni)
                acc[mi][ni] = __builtin_amdgcn_mfma_f32_16x16x32_bf16(af[mi], bf[ni], acc[mi][ni], 0, 0, 0);
    }
    __syncthreads();   // staging LDS dead; reuse for epilogue

    // ---- epilogue: row-softmax over j (in-regs) * exp(em), -> LDS -> store ---
    __hip_bfloat16* sW = (__hip_bfloat16*)(smem + wave * 9216);
    int mbase = mblk * 128 + wrow;
#pragma unroll
    for (int mi = 0; mi < 4; ++mi) {
#pragma unroll
        for (int rr = 0; rr < 4; ++rr) {
            float v0 = acc[mi][0][rr], v1 = acc[mi][1][rr];
            float v2 = acc[mi][2][rr], v3 = acc[mi][3][rr];
            float mx = fmaxf(fmaxf(v0, v1), fmaxf(v2, v3));
#pragma unroll
            for (int off = 1; off <= 8; off <<= 1) mx = fmaxf(mx, __shfl_xor(mx, off, 64));
            float e0 = __expf(v0 - mx), e1 = __expf(v1 - mx);
            float e2 = __expf(v2 - mx), e3 = __expf(v3 - mx);
            float sg = (e0 + e1) + (e2 + e3);
#pragma unroll
            for (int off = 1; off <= 8; off <<= 1) sg += __shfl_xor(sg, off, 64);
            int row = mi * 16 + g4 * 4 + rr;
            int m = mbase + row;
            float4 em4 = *(const float4*)(emX + (size_t)m * 64 + l15 * 4);
            float inv = 1.0f / sg;
            sW[row * 72 +  0 + l15] = __float2bfloat16(e0 * inv * em4.x);
            sW[row * 72 + 16 + l15] = __float2bfloat16(e1 * inv * em4.y);
            sW[row * 72 + 32 + l15] = __float2bfloat16(e2 * inv * em4.z);
            sW[row * 72 + 48 + l15] = __float2bfloat16(e3 * inv * em4.w);
        }
    }
    __syncthreads();
#pragma unroll
    for (int pass = 0; pass < 4; ++pass) {
        int r = pass * 16 + (lane >> 2);
        int q = lane & 3;
        int m = mblk * 128 + wrow + r;
        if (m < NT) {
            const uint4* src = (const uint4*)&sW[r * 72 + q * 16];
            uint4* dst = (uint4*)(Eg + (size_t)m * NCOLS + nblk * 128 + wcol + q * 16);
            dst[0] = src[0];
            dst[1] = src[1];
        }
    }
}

// ---------------- emission denominators: partial online-lse over vocab --------
__global__ __launch_bounds__(256) void dkern(const float* __restrict__ ec,
                                             const float* __restrict__ vw,
                                             float* __restrict__ partials) {
    __shared__ float ecT[64 * 64];
    int tid = threadIdx.x;
    for (int idx = tid; idx < 4096; idx += 256) {
        int k = idx >> 6, e = idx & 63;
        ecT[e * 64 + k] = ec[idx];
    }
    __syncthreads();
    int wave = tid >> 6, lane = tid & 63;
    int v0 = blockIdx.x * 125;
    float m = -1e30f, s = 0.f;
    for (int v = v0 + wave; v < v0 + 125; v += 4) {
        const float* row = vw + (size_t)v * 64;
        float acc = 0.f;
#pragma unroll
        for (int e = 0; e < 64; ++e) acc += ecT[e * 64 + lane] * row[e];
        float nm = fmaxf(m, acc);
        s = s * __expf(m - nm) + __expf(acc - nm);
        m = nm;
    }
    __shared__ float pm[4][64], ps[4][64];
    pm[wave][lane] = m; ps[wave][lane] = s;
    __syncthreads();
    if (tid < 64) {
        float M = pm[0][tid], Ssum = ps[0][tid];
#pragma unroll
        for (int w = 1; w < 4; ++w) {
            float m2 = pm[w][tid], s2 = ps[w][tid];
            float nm = fmaxf(M, m2);
            Ssum = Ssum * __expf(M - nm) + s2 * __expf(m2 - nm);
            M = nm;
        }
        partials[(blockIdx.x * 64 + tid) * 2]     = M;
        partials[(blockIdx.x * 64 + tid) * 2 + 1] = Ssum;
    }
}

__global__ __launch_bounds__(256) void dreduce(const float* __restrict__ partials,
                                               float* __restrict__ d) {
    __shared__ float pm[4][64], ps[4][64];
    int k = threadIdx.x & 63, part = threadIdx.x >> 6;
    float M = -1e30f, S = 0.f;
    for (int b = part; b < 256; b += 4) {
        float m2 = partials[(b * 64 + k) * 2];
        float s2 = partials[(b * 64 + k) * 2 + 1];
        float nm = fmaxf(M, m2);
        S = S * __expf(M - nm) + s2 * __expf(m2 - nm);
        M = nm;
    }
    pm[part][k] = M; ps[part][k] = S;
    __syncthreads();
    if (threadIdx.x < 64) {
        float Mm = pm[0][k], Ss = ps[0][k];
#pragma unroll
        for (int w = 1; w < 4; ++w) {
            float m2 = pm[w][k], s2 = ps[w][k];
            float nm = fmaxf(Mm, m2);
            Ss = Ss * __expf(Mm - nm) + s2 * __expf(m2 - nm);
            Mm = nm;
        }
        d[k] = Mm + __logf(Ss);
    }
}

// ---------------- emissions: exp(logit - lse), permuted layout ----------------
// position (l15*4 + g4) holds state j = g4*16 + l15 so gemm reads one float4/row
__global__ __launch_bounds__(256) void emit_kern(const int* __restrict__ x,
                                                 const float* __restrict__ ec,
                                                 const float* __restrict__ vw,
                                                 const float* __restrict__ d,
                                                 float* __restrict__ emX) {
    __shared__ float ecT[64 * 64];
    int tid = threadIdx.x;
    for (int idx = tid; idx < 4096; idx += 256) {
        int k = idx >> 6, e = idx & 63;
        ecT[e * 64 + k] = ec[idx];
    }
    __syncthreads();
    int wave = tid >> 6, lane = tid & 63;
    int nt = blockIdx.x * 4 + wave;      // grid = 4080 -> exactly 16320
    int n = nt / TSTEPS;
    int t = nt - n * TSTEPS;
    int tok = x[n * 256 + t + 1];
    const float* row = vw + (size_t)tok * 64;
    float acc = 0.f;
#pragma unroll
    for (int e = 0; e < 64; ++e) acc += ecT[e * 64 + lane] * row[e];
    emX[(size_t)nt * 64 + ((lane & 15) * 4 + (lane >> 4))] = __expf(acc - d[lane]);
}

// ---------------- chunk kernel: G_c = E_0 · E_1 ··· E_14 ----------------------
// Right-to-left: G <- E_t · G, t = 14..0. G kept transposed in LDS
// (sGT[j][k] = G[k][j], column-max normalized; gamma_j scales in sR).
// E_t staged async (global_load_lds, XOR-swizzled), double-buffered.
__global__ __launch_bounds__(256) void chunk_kern(const __hip_bfloat16* __restrict__ Eg,
                                                  __hip_bfloat16* __restrict__ Gout,
                                                  float* __restrict__ Rout) {
    int n = blockIdx.x, c = blockIdx.y;
    int tid = threadIdx.x, wave = tid >> 6, lane = tid & 63;
    int l15 = lane & 15, g4 = lane >> 4;

    __shared__ __align__(16) __hip_bfloat16 sGT[64 * 72];  // 9216 B
    __shared__ __align__(16) char sEt[2][8192];
    __shared__ float sR[64];

    for (int idx = tid; idx < 4096; idx += 256) {
        int j = idx >> 6, i = idx & 63;
        sGT[j * 72 + i] = __float2bfloat16(i == j ? 1.f : 0.f);
    }
    if (tid < 64) sR[tid] = 0.f;

    const char* tile0 = (const char*)(Eg + ((size_t)(n * TSTEPS + c * CLEN)) * NCOLS);
    int swz = ((lane & 7) ^ (lane >> 3)) * 16;   // global-side XOR chunk swizzle
    int lrow = lane >> 3;

    // stage E_14 into buf 0: wave stages rows [wave*16,+16)
#pragma unroll
    for (int g = 0; g < 2; ++g) {
        int rowbase = wave * 16 + g * 8;
        const char* gp = tile0 + 14 * 8192 + (rowbase + lrow) * 128 + swz;
        load_lds16(gp, (char*)sEt[0] + rowbase * 128);
    }
    __syncthreads();   // init + staged buf0 visible (barrier drains vmcnt)

    int buf = 0;
    for (int tl = 14; tl >= 0; --tl) {
        // prefetch E_{tl-1} into buf^1 (completes by the post-MFMA barrier)
        if (tl > 0) {
            const char* tp = tile0 + (size_t)(tl - 1) * 8192;
#pragma unroll
            for (int g = 0; g < 2; ++g) {
                int rowbase = wave * 16 + g * 8;
                load_lds16(tp + (rowbase + lrow) * 128 + swz,
                           (char*)sEt[buf ^ 1] + rowbase * 128);
            }
        }
        // P = E_tl · G ; wave w owns cols [w*16,+16), all 64 rows
        const char* eb = sEt[buf];
        f4v acc[4] = {};
#pragma unroll
        for (int kk = 0; kk < 2; ++kk) {
            s8v b = *(const s8v*)((const char*)sGT + (wave * 16 + l15) * 144 + kk * 64 + g4 * 16);
#pragma unroll
            for (int mi = 0; mi < 4; ++mi) {
                int eff = (kk * 4 + g4) ^ (l15 & 7);
                s8v a = *(const s8v*)(eb + (mi * 16 + l15) * 128 + eff * 16);
                acc[mi] = __builtin_amdgcn_mfma_f32_16x16x32_bf16(a, b, acc[mi], 0, 0, 0);
            }
        }
        __syncthreads();   // sGT reads done; prefetch landed

        // column-max normalize (col = wave*16 + l15, rows in-lane + g4 shfl)
        float mm = acc[0][0];
#pragma unroll
        for (int mi = 0; mi < 4; ++mi)
#pragma unroll
            for (int rr = 0; rr < 4; ++rr) mm = fmaxf(mm, acc[mi][rr]);
        mm = fmaxf(mm, __shfl_xor(mm, 16, 64));
        mm = fmaxf(mm, __shfl_xor(mm, 32, 64));
        mm = fmaxf(mm, 1e-35f);
        float inv = 1.0f / mm;
        int col = wave * 16 + l15;
#pragma unroll
        for (int mi = 0; mi < 4; ++mi) {
            union { __hip_bfloat16 h[4]; uint2 u; } pk;
#pragma unroll
            for (int rr = 0; rr < 4; ++rr) pk.h[rr] = __float2bfloat16(acc[mi][rr] * inv);
            *(uint2*)((char*)sGT + col * 144 + mi * 32 + g4 * 8) = pk.u;
        }
        if (g4 == 0) sR[col] += __logf(mm);
        __syncthreads();   // new G visible
        buf ^= 1;
    }

    // ---- output: Gout[i*64+j] = sGT[j][i], Rout = gamma ----
    __hip_bfloat16* go = Gout + ((size_t)(n * CHUNKS + c)) * 4096;
    for (int idx = tid; idx < 4096; idx += 256) {
        int i = idx >> 6, j = idx & 63;
        go[idx] = sGT[j * 72 + i];
    }
    if (tid < 64) Rout[(size_t)(n * CHUNKS + c) * 64 + tid] = sR[tid];
}

// ---------------- combine: alpha0 through 17 chunk matrices -------------------
__global__ __launch_bounds__(256) void combine_kern(const __hip_bfloat16* __restrict__ G,
                                                    const float* __restrict__ R,
                                                    const float* __restrict__ sw,
                                                    const float* __restrict__ sb,
                                                    float* __restrict__ out) {
    int n = blockIdx.x;
    int tid = threadIdx.x, wave = tid >> 6, lane = tid & 63;
    __shared__ float sA2[64], sV[64], pw[4][64];
    __shared__ float sMx;

    if (tid < 64) {
        float v = sw[tid] + sb[tid];
        float m = v;
        for (int off = 1; off < 64; off <<= 1) m = fmaxf(m, __shfl_xor(m, off, 64));
        float s = __expf(v - m);
        for (int off = 1; off < 64; off <<= 1) s += __shfl_xor(s, off, 64);
        sA2[tid] = v - (m + __logf(s));
    }
    __syncthreads();

    for (int c = 0; c < CHUNKS; ++c) {
        const __hip_bfloat16* Gc = G + ((size_t)(n * CHUNKS + c)) * 4096;
        const float* Rc = R + (size_t)(n * CHUNKS + c) * 64;
        if (tid < 64) {
            float t = sA2[tid];
            float m = t;
            for (int off = 1; off < 64; off <<= 1) m = fmaxf(m, __shfl_xor(m, off, 64));
            sV[tid] = __expf(t - m);
            if (tid == 0) sMx = m;
        }
        __syncthreads();
        float part = 0.f;
        int i0 = wave * 16;
#pragma unroll
        for (int r = 0; r < 16; ++r)
            part += sV[i0 + r] * __bfloat162float(Gc[(i0 + r) * 64 + lane]);
        pw[wave][lane] = part;
        __syncthreads();
        if (tid < 64) {
            float w = pw[0][tid] + pw[1][tid] + pw[2][tid] + pw[3][tid];
            sA2[tid] = sMx + __logf(w) + Rc[tid];   // column scale applied post
        }
        __syncthreads();
    }

    if (tid < 64) {
        float v = sA2[tid];
        float m = v;
        for (int off = 1; off < 64; off <<= 1) m = fmaxf(m, __shfl_xor(m, off, 64));
        float s = __expf(v - m);
        for (int off = 1; off < 64; off <<= 1) s += __shfl_xor(s, off, 64);
        if (tid == 0) atomicAdd(out, -(m + __logf(s)) * (1.0f / 64.0f));
    }
}

extern "C" void kernel_launch(void* const* d_in, const int* in_sizes, int n_in,
                              void* d_out, int out_size, void* d_ws, size_t ws_size,
                              hipStream_t stream) {
    const int*   x   = (const int*)d_in[0];
    const float* emb = (const float*)d_in[1];
    const float* Wt  = (const float*)d_in[2];
    const float* sw  = (const float*)d_in[3];
    const float* sb  = (const float*)d_in[4];
    const float* ec  = (const float*)d_in[5];
    const float* vw  = (const float*)d_in[6];
    float* out = (float*)d_out;
    char* ws = (char*)d_ws;

    __hip_bfloat16* Eg = (__hip_bfloat16*)ws;                          // 134,217,728 B (16384 rows)
    __hip_bfloat16* A  = (__hip_bfloat16*)(ws + 134217728ull);         //   4,194,304 B
    __hip_bfloat16* B  = (__hip_bfloat16*)(ws + 138412032ull);         //   1,048,576 B
    float* emXr        = (float*)(ws + 139460608ull);                  //   4,194,304 B (16384 rows pad)
    float* dvec        = (float*)(ws + 143654912ull);                  //       1,024 B
    float* partials    = (float*)(ws + 143655936ull);                  //     131,072 B
    __hip_bfloat16* Gc = (__hip_bfloat16*)(ws + 143787008ull);         //   8,912,896 B
    float* Rc          = (float*)(ws + 152699904ull);                  //     278,528 B
                                                                       // end 152,978,432

    hipMemsetAsync(out, 0, sizeof(float), stream);

    prep_a<<<NTPAD, 128, 0, stream>>>(x, emb, A);
    prep_b<<<NCOLS, 128, 0, stream>>>(Wt, B);
    dkern<<<256, 256, 0, stream>>>(ec, vw, partials);
    dreduce<<<1, 256, 0, stream>>>(partials, dvec);
    emit_kern<<<NT / 4, 256, 0, stream>>>(x, ec, vw, dvec, emXr);
    gemm_kern<<<dim3(NTPAD / 128, NCOLS / 128), 256, 0, stream>>>(A, B, emXr, Eg);
    chunk_kern<<<dim3(NSEQ, CHUNKS), 256, 0, stream>>>(Eg, Gc, Rc);
    combine_kern<<<NSEQ, 256, 0, stream>>>(Gc, Rc, sw, sb, out);
}